// Round 8
// baseline (519.345 us; speedup 1.0000x reference)
//
#include <hip/hip_runtime.h>
#include <hip/hip_bf16.h>
#include <math.h>

#define NGAUSS   50
#define HID      512
#define EMBD     256
#define NPID     10000         // 100*100 pair types
#define EBLK     64            // edges per block
#define GPAD     72            // u16 stride for g rows (144B)
#define EPAD     264           // u16 stride for emb stage rows in P-GEMM (528B)

typedef __attribute__((ext_vector_type(8))) short   bfrag;   // 8 bf16
typedef __attribute__((ext_vector_type(4))) float   facc;    // 4 f32
typedef __attribute__((ext_vector_type(8))) unsigned short u16x8;
typedef __attribute__((ext_vector_type(4))) unsigned short u16x4;

// ---- workspace layout (bytes) ----
#define PBF_OFF    0                         // u16 [10000*512]      10,240,000 (PERMUTED rows)
#define WC32_OFF   10240000                  // f32 [51*512] (row50 = combined bias) 104,448
#define W1BF_OFF   10344448                  // u16 [8*32*64*8]         262,144
#define WRBF_OFF   10606592                  // u16 [2*32*64*8]          65,536
#define WCBF_OFF   10672128                  // u16 [2*32*64*8]          65,536
#define W2F_OFF    10737664                  // u16 [16*64*8]            16,384

static __device__ __forceinline__ unsigned short f2bf(float f) {
    union { float f; unsigned u; } v; v.f = f;
    unsigned r = v.u + 0x7FFF + ((v.u >> 16) & 1);   // RTNE
    return (unsigned short)(r >> 16);
}
static __device__ __forceinline__ unsigned pack2bf(float a, float b) {
    __hip_bfloat162 t = __float22bfloat162_rn(make_float2(a, b));
    return *reinterpret_cast<unsigned*>(&t);
}
static __device__ __forceinline__ float bfu_lo(unsigned u) {
    union { unsigned u; float f; } v; v.u = u << 16; return v.f;
}
static __device__ __forceinline__ float bfu_hi(unsigned u) {
    union { unsigned u; float f; } v; v.u = u & 0xFFFF0000u; return v.f;
}

// ================= K0: Wcomb = W_rbf@W1top (fp32, row50 = b_rbf@W1top + b1), pack W1bot/Wrbf/W2 frags =================
// Fragment (kt,nt): elem j of lane l = W[k = kt*32 + (l>>4)*8 + j][col = nt*16 + (l&15)]
__global__ __launch_bounds__(256) void prep0(
    const float* __restrict__ W_rbf, const float* __restrict__ b_rbf,
    const float* __restrict__ W1, const float* __restrict__ b1,
    const float* __restrict__ W2, char* __restrict__ ws)
{
    const int b = blockIdx.x, tid = threadIdx.x;
    if (b < 102) {
        // ---- Wcomb fp32 rows 0..49, row 50 = b_rbf@W1top + b1 ----
        const int j = b >> 1, chalf = b & 1;
        const int c = chalf * 256 + tid;
        const float* row = (j < NGAUSS) ? &W_rbf[(size_t)j * HID] : b_rbf;
        float a0 = 0.f, a1 = 0.f, a2 = 0.f, a3 = 0.f;
        for (int k = 0; k < HID; k += 4) {
            a0 += row[k + 0] * W1[(size_t)(k + 0) * HID + c];
            a1 += row[k + 1] * W1[(size_t)(k + 1) * HID + c];
            a2 += row[k + 2] * W1[(size_t)(k + 2) * HID + c];
            a3 += row[k + 3] * W1[(size_t)(k + 3) * HID + c];
        }
        float acc = (a0 + a1) + (a2 + a3);
        ((float*)(ws + WC32_OFF))[j * HID + c] = (j < NGAUSS) ? acc : acc + b1[c];
    } else if (b < 166) {
        // ---- pack W1bot fragments: kt 0..7 over K=512..767 ----
        const int gid = (b - 102) * 256 + tid;          // [0, 16384)
        const int lane = gid & 63, tmp = gid >> 6, nt = tmp & 31, kt = tmp >> 5;
        const int c  = nt * 16 + (lane & 15);
        const int kb = HID + kt * 32 + ((lane >> 4) << 3);
        unsigned short* dst = (unsigned short*)(ws + W1BF_OFF);
        #pragma unroll
        for (int j = 0; j < 8; ++j)
            dst[(size_t)gid * 8 + j] = f2bf(W1[(size_t)(kb + j) * HID + c]);
    } else if (b < 182) {
        // ---- pack W_rbf fragments: kt 0..1 (K padded to 64; row 50 = b_rbf) ----
        const int gid = (b - 166) * 256 + tid;          // [0, 4096)
        const int lane = gid & 63, tmp = gid >> 6, nt = tmp & 31, kt = tmp >> 5;
        const int c  = nt * 16 + (lane & 15);
        const int kb = kt * 32 + ((lane >> 4) << 3);
        unsigned short* dst = (unsigned short*)(ws + WRBF_OFF);
        #pragma unroll
        for (int j = 0; j < 8; ++j) {
            int k = kb + j;
            unsigned short v = 0;
            if (k < NGAUSS)       v = f2bf(W_rbf[(size_t)k * HID + c]);
            else if (k == NGAUSS) v = f2bf(b_rbf[c]);
            dst[(size_t)gid * 8 + j] = v;
        }
    } else {
        // ---- pack W2^T fragments: kt 0..15, heads padded to 16 ----
        const int gid = (b - 182) * 256 + tid;          // [0, 1024)
        const int lane = gid & 63, kt = gid >> 6;
        const int col = lane & 15;
        const int kb  = kt * 32 + ((lane >> 4) << 3);
        unsigned short* dst = (unsigned short*)(ws + W2F_OFF);
        #pragma unroll
        for (int j = 0; j < 8; ++j)
            dst[(size_t)gid * 8 + j] = (col < 8) ? f2bf(W2[(size_t)(kb + j) * 8 + col]) : (unsigned short)0;
    }
}

// ================= K1: pack Wcomb frags (row50 = bias) + P = emb_table @ W1bot =================
// P rows stored PERMUTED: element for hidden col c goes to offset W*64 + L*16 + M*4 + J
// where c = W*64 + M*16 + L*4 + J  -> each main-kernel thread's 8 values are 16B contiguous.
__global__ __launch_bounds__(512) void prep1(
    const float* __restrict__ emb_table, char* __restrict__ ws)
{
    const int b = blockIdx.x, t = threadIdx.x;
    if (b < 8) {
        const int gid = b * 512 + t;                    // [0, 4096)
        const int lane = gid & 63, tmp = gid >> 6, nt = tmp & 31, kt = tmp >> 5;
        const int c  = nt * 16 + (lane & 15);
        const int kb = kt * 32 + ((lane >> 4) << 3);
        const float* wc = (const float*)(ws + WC32_OFF);
        unsigned short* dst = (unsigned short*)(ws + WCBF_OFF);
        #pragma unroll
        for (int j = 0; j < 8; ++j) {
            int k = kb + j;
            dst[(size_t)gid * 8 + j] = (k <= NGAUSS) ? f2bf(wc[k * HID + c]) : (unsigned short)0;
        }
        return;
    }
    __shared__ unsigned short s_e[64 * EPAD];
    const int pb = b - 8;                               // 0..156
    const int lane = t & 63, w = t >> 6;
    const int lq = lane >> 4, lr = lane & 15;
    {
        int row = t >> 3;
        int grow = pb * 64 + row; if (grow >= NPID) grow = NPID - 1;
        int c0 = (t & 7) * 32;
        #pragma unroll
        for (int ii = 0; ii < 8; ++ii) {
            const float4 v = *(const float4*)&emb_table[(size_t)grow * EMBD + c0 + ii * 4];
            u16x4 bv; bv[0] = f2bf(v.x); bv[1] = f2bf(v.y); bv[2] = f2bf(v.z); bv[3] = f2bf(v.w);
            *(u16x4*)&s_e[row * EPAD + c0 + ii * 4] = bv;
        }
    }
    __syncthreads();
    const int ntb = w * 4;
    const unsigned short* W1bf = (const unsigned short*)(ws + W1BF_OFF);
    unsigned short* Pbf = (unsigned short*)(ws + PBF_OFF);
    facc acc[4][4] = {};
    for (int kt = 0; kt < 8; ++kt) {
        bfrag a[4];
        #pragma unroll
        for (int mt = 0; mt < 4; ++mt)
            a[mt] = *(const bfrag*)&s_e[(mt * 16 + lr) * EPAD + kt * 32 + lq * 8];
        #pragma unroll
        for (int ntl = 0; ntl < 4; ++ntl) {
            bfrag bv = *(const bfrag*)&W1bf[((size_t)(kt * 32 + ntb + ntl) * 64 + lane) * 8];
            #pragma unroll
            for (int mt = 0; mt < 4; ++mt)
                acc[mt][ntl] = __builtin_amdgcn_mfma_f32_16x16x32_bf16(a[mt], bv, acc[mt][ntl], 0, 0, 0);
        }
    }
    #pragma unroll
    for (int ntl = 0; ntl < 4; ++ntl) {
        const int col = (ntb + ntl) * 16 + lr;
        const int Wd = col >> 6, Md = (col >> 4) & 3, Ld = (col >> 2) & 3, Jd = col & 3;
        const int off = Wd * 64 + Ld * 16 + Md * 4 + Jd;   // permuted position
        #pragma unroll
        for (int mt = 0; mt < 4; ++mt) {
            #pragma unroll
            for (int r = 0; r < 4; ++r) {
                int grow = pb * 64 + mt * 16 + lq * 4 + r;
                if (grow < NPID) Pbf[(size_t)grow * HID + off] = f2bf(acc[mt][ntl][r]);
            }
        }
    }
}

// ================= main fused kernel: 1024 threads, 16 waves (32 hidden cols each); TRANSPOSED GEMMs =================
// h stored frag-linear: s_buf[nt4*8192 + (kt*64 + l)*8 + j], kt = hidden-col>>5.
__global__ __launch_bounds__(1024, 8) void pair_embed_mfma(
    const int* __restrict__ anum,
    const int* __restrict__ row_index,
    const int* __restrict__ col_index,
    const float* __restrict__ dist,
    const float* __restrict__ b2,
    const char* __restrict__ ws,
    float* __restrict__ out,
    int n)
{
    extern __shared__ char smem[];
    unsigned short* s_buf = (unsigned short*)smem;                    // 64 KB frag-linear h
    unsigned short* s_g   = (unsigned short*)(smem + 65536);          // [64][GPAD] (phases 1-3)
    float*          s_scr = (float*)(smem + 65536);                   // 12 KB phase-4 partials (alias)
    float*          s_d   = (float*)(smem + 65536 + 12288);
    int*            s_pid = (int*)(smem + 65536 + 12288 + 256);

    const unsigned short* Pbf   = (const unsigned short*)(ws + PBF_OFF);
    const unsigned short* Wrbff = (const unsigned short*)(ws + WRBF_OFF);
    const unsigned short* Wcbf  = (const unsigned short*)(ws + WCBF_OFF);
    const unsigned short* W2f   = (const unsigned short*)(ws + W2F_OFF);

    const int t = threadIdx.x, lane = t & 63, w = t >> 6;   // w 0..15
    const int e0 = blockIdx.x * EBLK;
    const int lq = lane >> 4, lr = lane & 15;

    // ---- phase 0: metadata ----
    if (t < EBLK) {
        int e = e0 + t; if (e >= n) e = n - 1;
        s_d[t] = dist[e];
        s_pid[t] = anum[row_index[e]] + 100 * anum[col_index[e]];
    }
    __syncthreads();

    // ---- tile-0 P load EARLY (one uint4 = this thread's 8 cols, permuted-contiguous) ----
    const int pbase = (w >> 1) * 64 + lq * 16 + (w & 1) * 8;
    uint4 q = *(const uint4*)&Pbf[(unsigned)s_pid[lr] * 512u + pbase];

    // ---- phase 1: gaussians -> s_g (K padded to 64; slot 50 = 1.0 for bias row) ----
    {
        const float sp = 12.0f / 49.0f;
        const float coeff = -0.5f / (sp * sp);
        int e = t >> 4, j0 = (t & 15) * 4;
        float d = s_d[e];
        float gv[4];
        #pragma unroll
        for (int j = 0; j < 4; ++j) {
            int jj = j0 + j;
            float v = d - (float)jj * sp;
            gv[j] = (jj < NGAUSS) ? __expf(coeff * v * v) : (jj == NGAUSS ? 1.0f : 0.0f);
        }
        uint2 pk;
        pk.x = pack2bf(gv[0], gv[1]); pk.y = pack2bf(gv[2], gv[3]);
        *(uint2*)&s_g[e * GPAD + j0] = pk;
    }

    // ---- A-operand fragments (wave's 32 hidden cols): 8 frags = 32 VGPRs ----
    const int mtb = w * 2;
    bfrag aR[2][2], aC[2][2];
    #pragma unroll
    for (int kt = 0; kt < 2; ++kt)
        #pragma unroll
        for (int m = 0; m < 2; ++m) {
            aR[kt][m] = *(const bfrag*)&Wrbff[((size_t)(kt * 32 + mtb + m) * 64 + lane) * 8];
            aC[kt][m] = *(const bfrag*)&Wcbf [((size_t)(kt * 32 + mtb + m) * 64 + lane) * 8];
        }
    __syncthreads();

    // h-store base (frag-linear): kt = w, writes at hbase + nt4*8192 + m*256 (uint2 each)
    const int hbase = w * 512 + (lq >> 1) * 128 + lr * 8 + (lq & 1) * 4;

    // ---- phases 2+3: per 16-edge tile: twin MFMAs + packed-f32 epilogue (P pipelined 1 ahead) ----
    for (int nt4 = 0; nt4 < 4; ++nt4) {
        uint4 qn;
        if (nt4 < 3)
            qn = *(const uint4*)&Pbf[(unsigned)s_pid[(nt4 + 1) * 16 + lr] * 512u + pbase];
        const int e = nt4 * 16 + lr;
        bfrag g0 = *(const bfrag*)&s_g[e * GPAD + lq * 8];
        bfrag g1 = *(const bfrag*)&s_g[e * GPAD + 32 + lq * 8];
        facc racc[2] = {}, cacc[2] = {};
        #pragma unroll
        for (int m = 0; m < 2; ++m) {
            racc[m] = __builtin_amdgcn_mfma_f32_16x16x32_bf16(aR[0][m], g0, racc[m], 0, 0, 0);
            cacc[m] = __builtin_amdgcn_mfma_f32_16x16x32_bf16(aC[0][m], g0, cacc[m], 0, 0, 0);
        }
        #pragma unroll
        for (int m = 0; m < 2; ++m) {
            racc[m] = __builtin_amdgcn_mfma_f32_16x16x32_bf16(aR[1][m], g1, racc[m], 0, 0, 0);
            cacc[m] = __builtin_amdgcn_mfma_f32_16x16x32_bf16(aC[1][m], g1, cacc[m], 0, 0, 0);
        }
        // epilogue: pre = cacc + P ; h = pre * sigmoid(pre) * rbf ; packed f32 math
        facc pf0, pf1;
        pf0[0] = bfu_lo(q.x); pf0[1] = bfu_hi(q.x); pf0[2] = bfu_lo(q.y); pf0[3] = bfu_hi(q.y);
        pf1[0] = bfu_lo(q.z); pf1[1] = bfu_hi(q.z); pf1[2] = bfu_lo(q.w); pf1[3] = bfu_hi(q.w);
        unsigned short* hb = s_buf + nt4 * 8192 + hbase;
        {
            facc pre = cacc[0] + pf0;
            facc nx  = pre * -1.442695040888963f;          // v_pk_mul
            facc ex;
            #pragma unroll
            for (int i = 0; i < 4; ++i) ex[i] = exp2f(nx[i]);   // v_exp each
            facc den = ex + 1.0f;                           // v_pk_add
            facc sg;
            #pragma unroll
            for (int i = 0; i < 4; ++i) sg[i] = __builtin_amdgcn_rcpf(den[i]);
            facc h = pre * sg * racc[0];                    // v_pk_mul x2
            uint2 hw; hw.x = pack2bf(h[0], h[1]); hw.y = pack2bf(h[2], h[3]);
            *(uint2*)&hb[0] = hw;
        }
        {
            facc pre = cacc[1] + pf1;
            facc nx  = pre * -1.442695040888963f;
            facc ex;
            #pragma unroll
            for (int i = 0; i < 4; ++i) ex[i] = exp2f(nx[i]);
            facc den = ex + 1.0f;
            facc sg;
            #pragma unroll
            for (int i = 0; i < 4; ++i) sg[i] = __builtin_amdgcn_rcpf(den[i]);
            facc h = pre * sg * racc[1];
            uint2 hw; hw.x = pack2bf(h[0], h[1]); hw.y = pack2bf(h[2], h[3]);
            *(uint2*)&hb[256] = hw;
        }
        if (nt4 < 3) q = qn;
    }
    __syncthreads();

    // ---- phase 4: out[head][e] = (W2^T @ h^T) + b2; 16 waves = nt(4) x ks(4), 4 kt each ----
    {
        const int nt4 = w & 3;          // 16-edge tile
        const int ks  = w >> 2;         // k-quarter (4 kt each; K=512 -> 16 kt)
        const unsigned short* hbuf = s_buf + nt4 * 8192;
        facc a4 = {};
        #pragma unroll
        for (int kq = 0; kq < 4; ++kq) {
            int kt = ks * 4 + kq;
            bfrag hfrag = *(const bfrag*)&hbuf[(kt * 64 + lane) * 8];
            bfrag wfrag = *(const bfrag*)&W2f[((size_t)kt * 64 + lane) * 8];
            a4 = __builtin_amdgcn_mfma_f32_16x16x32_bf16(wfrag, hfrag, a4, 0, 0, 0);
        }
        if (ks > 0) *(facc*)&s_scr[(((ks - 1) * 4 + nt4) * 64 + lane) * 4] = a4;
        __syncthreads();
        if (ks == 0) {
            #pragma unroll
            for (int p = 0; p < 3; ++p) {
                facc oth = *(const facc*)&s_scr[((size_t)(p * 4 + nt4) * 64 + lane) * 4];
                a4 += oth;
            }
            if (lq < 2) {
                const int e = e0 + nt4 * 16 + lr;
                if (e < n) {
                    #pragma unroll
                    for (int r = 0; r < 4; ++r) {
                        int head = lq * 4 + r;
                        out[(size_t)head * n + e] = a4[r] + b2[head];
                    }
                }
            }
        }
    }
}

extern "C" void kernel_launch(void* const* d_in, const int* in_sizes, int n_in,
                              void* d_out, int out_size, void* d_ws, size_t ws_size,
                              hipStream_t stream) {
    const int*   anum      = (const int*)d_in[0];
    const int*   row_index = (const int*)d_in[1];
    const int*   col_index = (const int*)d_in[2];
    const float* dist      = (const float*)d_in[3];
    const float* W_rbf     = (const float*)d_in[4];
    const float* b_rbf     = (const float*)d_in[5];
    const float* emb_table = (const float*)d_in[6];
    const float* W1        = (const float*)d_in[7];
    const float* b1        = (const float*)d_in[8];
    const float* W2        = (const float*)d_in[9];
    const float* b2        = (const float*)d_in[10];
    float* out = (float*)d_out;
    char* ws = (char*)d_ws;

    const int n_edges = in_sizes[3];

    prep0<<<186, 256, 0, stream>>>(W_rbf, b_rbf, W1, b1, W2, ws);
    prep1<<<8 + 157, 512, 0, stream>>>(emb_table, ws);

    const int grid = (n_edges + EBLK - 1) / EBLK;
    const size_t lds_bytes = 65536 + 12288 + 256 + 256;   // 78336 -> 2 blocks/CU
    pair_embed_mfma<<<grid, 1024, lds_bytes, stream>>>(
        anum, row_index, col_index, dist, b2, ws, out, n_edges);
}

// Round 9
// 195.430 us; speedup vs baseline: 2.6574x; 2.6574x over previous
//
#include <hip/hip_runtime.h>
#include <hip/hip_bf16.h>
#include <math.h>

#define NGAUSS   50
#define HID      512
#define EMBD     256
#define NPID     10000         // 100*100 pair types
#define EBLK     32            // edges per block
#define GPAD     72            // u16 stride for g rows (144B)
#define EPAD     264           // u16 stride for emb stage rows in P-GEMM (528B)

typedef __attribute__((ext_vector_type(8))) short   bfrag;   // 8 bf16
typedef __attribute__((ext_vector_type(4))) float   facc;    // 4 f32
typedef __attribute__((ext_vector_type(8))) unsigned short u16x8;
typedef __attribute__((ext_vector_type(4))) unsigned short u16x4;

// ---- workspace layout (bytes) ----
#define PBF_OFF    0                         // u16 [10000*512]      10,240,000 (PERMUTED rows)
#define WC32_OFF   10240000                  // f32 [51*512] (row50 = combined bias) 104,448
#define W1BF_OFF   10344448                  // u16 [8*32*64*8]         262,144
#define WRBF_OFF   10606592                  // u16 [2*32*64*8]          65,536
#define WCBF_OFF   10672128                  // u16 [2*32*64*8]          65,536
#define W2F_OFF    10737664                  // u16 [16*64*8]            16,384

static __device__ __forceinline__ unsigned short f2bf(float f) {
    union { float f; unsigned u; } v; v.f = f;
    unsigned r = v.u + 0x7FFF + ((v.u >> 16) & 1);   // RTNE
    return (unsigned short)(r >> 16);
}
static __device__ __forceinline__ unsigned pack2bf(float a, float b) {
    __hip_bfloat162 t = __float22bfloat162_rn(make_float2(a, b));
    return *reinterpret_cast<unsigned*>(&t);
}
static __device__ __forceinline__ float bfu_lo(unsigned u) {
    union { unsigned u; float f; } v; v.u = u << 16; return v.f;
}
static __device__ __forceinline__ float bfu_hi(unsigned u) {
    union { unsigned u; float f; } v; v.u = u & 0xFFFF0000u; return v.f;
}

// ================= K0: Wcomb = W_rbf@W1top (fp32, row50 = b_rbf@W1top + b1), pack W1bot/Wrbf/W2 frags =================
// Fragment (kt,nt): elem j of lane l = W[k = kt*32 + (l>>4)*8 + j][col = nt*16 + (l&15)]
__global__ __launch_bounds__(256) void prep0(
    const float* __restrict__ W_rbf, const float* __restrict__ b_rbf,
    const float* __restrict__ W1, const float* __restrict__ b1,
    const float* __restrict__ W2, char* __restrict__ ws)
{
    const int b = blockIdx.x, tid = threadIdx.x;
    if (b < 102) {
        const int j = b >> 1, chalf = b & 1;
        const int c = chalf * 256 + tid;
        const float* row = (j < NGAUSS) ? &W_rbf[(size_t)j * HID] : b_rbf;
        float a0 = 0.f, a1 = 0.f, a2 = 0.f, a3 = 0.f;
        for (int k = 0; k < HID; k += 4) {
            a0 += row[k + 0] * W1[(size_t)(k + 0) * HID + c];
            a1 += row[k + 1] * W1[(size_t)(k + 1) * HID + c];
            a2 += row[k + 2] * W1[(size_t)(k + 2) * HID + c];
            a3 += row[k + 3] * W1[(size_t)(k + 3) * HID + c];
        }
        float acc = (a0 + a1) + (a2 + a3);
        ((float*)(ws + WC32_OFF))[j * HID + c] = (j < NGAUSS) ? acc : acc + b1[c];
    } else if (b < 166) {
        const int gid = (b - 102) * 256 + tid;          // [0, 16384)
        const int lane = gid & 63, tmp = gid >> 6, nt = tmp & 31, kt = tmp >> 5;
        const int c  = nt * 16 + (lane & 15);
        const int kb = HID + kt * 32 + ((lane >> 4) << 3);
        unsigned short* dst = (unsigned short*)(ws + W1BF_OFF);
        #pragma unroll
        for (int j = 0; j < 8; ++j)
            dst[(size_t)gid * 8 + j] = f2bf(W1[(size_t)(kb + j) * HID + c]);
    } else if (b < 182) {
        const int gid = (b - 166) * 256 + tid;          // [0, 4096)
        const int lane = gid & 63, tmp = gid >> 6, nt = tmp & 31, kt = tmp >> 5;
        const int c  = nt * 16 + (lane & 15);
        const int kb = kt * 32 + ((lane >> 4) << 3);
        unsigned short* dst = (unsigned short*)(ws + WRBF_OFF);
        #pragma unroll
        for (int j = 0; j < 8; ++j) {
            int k = kb + j;
            unsigned short v = 0;
            if (k < NGAUSS)       v = f2bf(W_rbf[(size_t)k * HID + c]);
            else if (k == NGAUSS) v = f2bf(b_rbf[c]);
            dst[(size_t)gid * 8 + j] = v;
        }
    } else {
        const int gid = (b - 182) * 256 + tid;          // [0, 1024)
        const int lane = gid & 63, kt = gid >> 6;
        const int col = lane & 15;
        const int kb  = kt * 32 + ((lane >> 4) << 3);
        unsigned short* dst = (unsigned short*)(ws + W2F_OFF);
        #pragma unroll
        for (int j = 0; j < 8; ++j)
            dst[(size_t)gid * 8 + j] = (col < 8) ? f2bf(W2[(size_t)(kb + j) * 8 + col]) : (unsigned short)0;
    }
}

// ================= K1: pack Wcomb frags (row50 = bias) + P = emb_table @ W1bot =================
// P rows stored PERMUTED: element for hidden col c = Wd*64 + Md*16 + Ld*4 + Jd
// goes to offset Wd*64 + Ld*16 + Md*4 + Jd  -> each main-kernel thread's 16 values
// for (w,lq) are 32B contiguous, uint2 per m.
__global__ __launch_bounds__(512) void prep1(
    const float* __restrict__ emb_table, char* __restrict__ ws)
{
    const int b = blockIdx.x, t = threadIdx.x;
    if (b < 8) {
        const int gid = b * 512 + t;                    // [0, 4096)
        const int lane = gid & 63, tmp = gid >> 6, nt = tmp & 31, kt = tmp >> 5;
        const int c  = nt * 16 + (lane & 15);
        const int kb = kt * 32 + ((lane >> 4) << 3);
        const float* wc = (const float*)(ws + WC32_OFF);
        unsigned short* dst = (unsigned short*)(ws + WCBF_OFF);
        #pragma unroll
        for (int j = 0; j < 8; ++j) {
            int k = kb + j;
            dst[(size_t)gid * 8 + j] = (k <= NGAUSS) ? f2bf(wc[k * HID + c]) : (unsigned short)0;
        }
        return;
    }
    __shared__ unsigned short s_e[64 * EPAD];
    const int pb = b - 8;                               // 0..156
    const int lane = t & 63, w = t >> 6;
    const int lq = lane >> 4, lr = lane & 15;
    {
        int row = t >> 3;
        int grow = pb * 64 + row; if (grow >= NPID) grow = NPID - 1;
        int c0 = (t & 7) * 32;
        #pragma unroll
        for (int ii = 0; ii < 8; ++ii) {
            const float4 v = *(const float4*)&emb_table[(size_t)grow * EMBD + c0 + ii * 4];
            u16x4 bv; bv[0] = f2bf(v.x); bv[1] = f2bf(v.y); bv[2] = f2bf(v.z); bv[3] = f2bf(v.w);
            *(u16x4*)&s_e[row * EPAD + c0 + ii * 4] = bv;
        }
    }
    __syncthreads();
    const int ntb = w * 4;
    const unsigned short* W1bf = (const unsigned short*)(ws + W1BF_OFF);
    unsigned short* Pbf = (unsigned short*)(ws + PBF_OFF);
    facc acc[4][4] = {};
    for (int kt = 0; kt < 8; ++kt) {
        bfrag a[4];
        #pragma unroll
        for (int mt = 0; mt < 4; ++mt)
            a[mt] = *(const bfrag*)&s_e[(mt * 16 + lr) * EPAD + kt * 32 + lq * 8];
        #pragma unroll
        for (int ntl = 0; ntl < 4; ++ntl) {
            bfrag bv = *(const bfrag*)&W1bf[((size_t)(kt * 32 + ntb + ntl) * 64 + lane) * 8];
            #pragma unroll
            for (int mt = 0; mt < 4; ++mt)
                acc[mt][ntl] = __builtin_amdgcn_mfma_f32_16x16x32_bf16(a[mt], bv, acc[mt][ntl], 0, 0, 0);
        }
    }
    #pragma unroll
    for (int ntl = 0; ntl < 4; ++ntl) {
        const int col = (ntb + ntl) * 16 + lr;
        const int Wd = col >> 6, Md = (col >> 4) & 3, Ld = (col >> 2) & 3, Jd = col & 3;
        const int off = Wd * 64 + Ld * 16 + Md * 4 + Jd;   // permuted position
        #pragma unroll
        for (int mt = 0; mt < 4; ++mt) {
            #pragma unroll
            for (int r = 0; r < 4; ++r) {
                int grow = pb * 64 + mt * 16 + lq * 4 + r;
                if (grow < NPID) Pbf[(size_t)grow * HID + off] = f2bf(acc[mt][ntl][r]);
            }
        }
    }
}

// ================= main fused kernel: 512 threads, 8 waves x 64 cols; EBLK=32; m-outer loop =================
// h frag-linear: s_buf[tile*8192 + (kt*64 + l)*8 + j]; per-thread write at
//   tile*8192 + w*1024 + m*256 + (lq>>1)*128 + lr*8 + (lq&1)*4  (uint2)
__global__ __launch_bounds__(512, 6) void pair_embed_mfma(
    const int* __restrict__ anum,
    const int* __restrict__ row_index,
    const int* __restrict__ col_index,
    const float* __restrict__ dist,
    const float* __restrict__ b2,
    const char* __restrict__ ws,
    float* __restrict__ out,
    int n)
{
    extern __shared__ char smem[];
    unsigned short* s_buf = (unsigned short*)smem;                    // 32 KB frag-linear h (2 tiles)
    unsigned short* s_g   = (unsigned short*)(smem + 32768);          // [32][GPAD] = 4608 B
    float*          s_scr = (float*)(smem + 32768);                   // 6 KB phase-4 partials (ALIAS, used after main barrier)
    float*          s_d   = (float*)(smem + 32768 + 4608);
    int*            s_pid = (int*)(smem + 32768 + 4608 + 128);

    const unsigned short* Pbf   = (const unsigned short*)(ws + PBF_OFF);
    const unsigned short* Wrbff = (const unsigned short*)(ws + WRBF_OFF);
    const unsigned short* Wcbf  = (const unsigned short*)(ws + WCBF_OFF);
    const unsigned short* W2f   = (const unsigned short*)(ws + W2F_OFF);

    const int t = threadIdx.x, lane = t & 63, w = t >> 6;   // w 0..7
    const int e0 = blockIdx.x * EBLK;
    const int lq = lane >> 4, lr = lane & 15;

    // ---- phase 0: metadata ----
    if (t < EBLK) {
        int e = e0 + t; if (e >= n) e = n - 1;
        s_d[t] = dist[e];
        s_pid[t] = anum[row_index[e]] + 100 * anum[col_index[e]];
    }
    __syncthreads();

    // ---- phase 1: gaussians -> s_g (K padded to 64; slot 50 = 1.0 for bias row) ----
    {
        const float sp = 12.0f / 49.0f;
        const float coeff = -0.5f / (sp * sp);
        int e = t >> 4, j0 = (t & 15) * 4;
        float d = s_d[e];
        float gv[4];
        #pragma unroll
        for (int j = 0; j < 4; ++j) {
            int jj = j0 + j;
            float v = d - (float)jj * sp;
            gv[j] = (jj < NGAUSS) ? __expf(coeff * v * v) : (jj == NGAUSS ? 1.0f : 0.0f);
        }
        uint2 pk;
        pk.x = pack2bf(gv[0], gv[1]); pk.y = pack2bf(gv[2], gv[3]);
        *(uint2*)&s_g[e * GPAD + j0] = pk;
    }

    // pid->P byte bases for this thread's two tiles (u16 index)
    const unsigned poff0 = (unsigned)s_pid[lr] * 512u;
    const unsigned poff1 = (unsigned)s_pid[16 + lr] * 512u;
    const int pcol = w * 64 + lq * 16;      // + m*4
    __syncthreads();    // g visible

    // ---- main: m-outer (4 hidden 16-col tiles per wave), 2 edge-tiles inner ----
    for (int m = 0; m < 4; ++m) {
        // P loads for this m (consumed ~after the MFMAs)
        const uint2 p0 = *(const uint2*)&Pbf[poff0 + pcol + m * 4];
        const uint2 p1 = *(const uint2*)&Pbf[poff1 + pcol + m * 4];
        // A-fragments for (m): 4 frags = 16 VGPRs live
        const int nt = w * 4 + m;
        const bfrag aR0 = *(const bfrag*)&Wrbff[((size_t)(0 * 32 + nt) * 64 + lane) * 8];
        const bfrag aR1 = *(const bfrag*)&Wrbff[((size_t)(1 * 32 + nt) * 64 + lane) * 8];
        const bfrag aC0 = *(const bfrag*)&Wcbf [((size_t)(0 * 32 + nt) * 64 + lane) * 8];
        const bfrag aC1 = *(const bfrag*)&Wcbf [((size_t)(1 * 32 + nt) * 64 + lane) * 8];

        facc racc0 = {}, cacc0 = {}, racc1 = {}, cacc1 = {};
        {
            const bfrag g0 = *(const bfrag*)&s_g[lr * GPAD + lq * 8];
            const bfrag g1 = *(const bfrag*)&s_g[lr * GPAD + 32 + lq * 8];
            racc0 = __builtin_amdgcn_mfma_f32_16x16x32_bf16(aR0, g0, racc0, 0, 0, 0);
            cacc0 = __builtin_amdgcn_mfma_f32_16x16x32_bf16(aC0, g0, cacc0, 0, 0, 0);
            racc0 = __builtin_amdgcn_mfma_f32_16x16x32_bf16(aR1, g1, racc0, 0, 0, 0);
            cacc0 = __builtin_amdgcn_mfma_f32_16x16x32_bf16(aC1, g1, cacc0, 0, 0, 0);
        }
        {
            const bfrag g0 = *(const bfrag*)&s_g[(16 + lr) * GPAD + lq * 8];
            const bfrag g1 = *(const bfrag*)&s_g[(16 + lr) * GPAD + 32 + lq * 8];
            racc1 = __builtin_amdgcn_mfma_f32_16x16x32_bf16(aR0, g0, racc1, 0, 0, 0);
            cacc1 = __builtin_amdgcn_mfma_f32_16x16x32_bf16(aC0, g0, cacc1, 0, 0, 0);
            racc1 = __builtin_amdgcn_mfma_f32_16x16x32_bf16(aR1, g1, racc1, 0, 0, 0);
            cacc1 = __builtin_amdgcn_mfma_f32_16x16x32_bf16(aC1, g1, cacc1, 0, 0, 0);
        }

        unsigned short* hb = s_buf + w * 1024 + m * 256 + (lq >> 1) * 128 + lr * 8 + (lq & 1) * 4;
        {   // tile 0 epilogue
            facc pf; pf[0] = bfu_lo(p0.x); pf[1] = bfu_hi(p0.x); pf[2] = bfu_lo(p0.y); pf[3] = bfu_hi(p0.y);
            facc pre = cacc0 + pf;
            facc nx  = pre * -1.442695040888963f;
            facc ex;
            #pragma unroll
            for (int i = 0; i < 4; ++i) ex[i] = exp2f(nx[i]);
            facc den = ex + 1.0f;
            facc sg;
            #pragma unroll
            for (int i = 0; i < 4; ++i) sg[i] = __builtin_amdgcn_rcpf(den[i]);
            facc h = pre * sg * racc0;
            uint2 hw; hw.x = pack2bf(h[0], h[1]); hw.y = pack2bf(h[2], h[3]);
            *(uint2*)&hb[0] = hw;
        }
        {   // tile 1 epilogue
            facc pf; pf[0] = bfu_lo(p1.x); pf[1] = bfu_hi(p1.x); pf[2] = bfu_lo(p1.y); pf[3] = bfu_hi(p1.y);
            facc pre = cacc1 + pf;
            facc nx  = pre * -1.442695040888963f;
            facc ex;
            #pragma unroll
            for (int i = 0; i < 4; ++i) ex[i] = exp2f(nx[i]);
            facc den = ex + 1.0f;
            facc sg;
            #pragma unroll
            for (int i = 0; i < 4; ++i) sg[i] = __builtin_amdgcn_rcpf(den[i]);
            facc h = pre * sg * racc1;
            uint2 hw; hw.x = pack2bf(h[0], h[1]); hw.y = pack2bf(h[2], h[3]);
            *(uint2*)&hb[8192] = hw;
        }
    }
    __syncthreads();

    // ---- phase 4: out[head][e] = (W2^T @ h^T) + b2; waves = nt(2) x ks(4), 4 kt each ----
    {
        const int nt4 = w & 1;          // 16-edge tile
        const int ks  = w >> 1;         // k-quarter (4 kt each; K=512 -> 16 kt)
        const unsigned short* hbuf = s_buf + nt4 * 8192;
        facc a4 = {};
        #pragma unroll
        for (int kq = 0; kq < 4; ++kq) {
            int kt = ks * 4 + kq;
            bfrag hfrag = *(const bfrag*)&hbuf[(kt * 64 + lane) * 8];
            bfrag wfrag = *(const bfrag*)&W2f[((size_t)kt * 64 + lane) * 8];
            a4 = __builtin_amdgcn_mfma_f32_16x16x32_bf16(wfrag, hfrag, a4, 0, 0, 0);
        }
        if (ks > 0) *(facc*)&s_scr[(((ks - 1) * 2 + nt4) * 64 + lane) * 4] = a4;
        __syncthreads();
        if (ks == 0) {
            #pragma unroll
            for (int p = 0; p < 3; ++p) {
                facc oth = *(const facc*)&s_scr[((size_t)(p * 2 + nt4) * 64 + lane) * 4];
                a4 += oth;
            }
            if (lq < 2) {
                const int e = e0 + nt4 * 16 + lr;
                if (e < n) {
                    #pragma unroll
                    for (int r = 0; r < 4; ++r) {
                        int head = lq * 4 + r;
                        out[(size_t)head * n + e] = a4[r] + b2[head];
                    }
                }
            }
        }
    }
}

extern "C" void kernel_launch(void* const* d_in, const int* in_sizes, int n_in,
                              void* d_out, int out_size, void* d_ws, size_t ws_size,
                              hipStream_t stream) {
    const int*   anum      = (const int*)d_in[0];
    const int*   row_index = (const int*)d_in[1];
    const int*   col_index = (const int*)d_in[2];
    const float* dist      = (const float*)d_in[3];
    const float* W_rbf     = (const float*)d_in[4];
    const float* b_rbf     = (const float*)d_in[5];
    const float* emb_table = (const float*)d_in[6];
    const float* W1        = (const float*)d_in[7];
    const float* b1        = (const float*)d_in[8];
    const float* W2        = (const float*)d_in[9];
    const float* b2        = (const float*)d_in[10];
    float* out = (float*)d_out;
    char* ws = (char*)d_ws;

    const int n_edges = in_sizes[3];

    prep0<<<186, 256, 0, stream>>>(W_rbf, b_rbf, W1, b1, W2, ws);
    prep1<<<8 + 157, 512, 0, stream>>>(emb_table, ws);

    const int grid = (n_edges + EBLK - 1) / EBLK;
    // s_buf 32768 + max(s_g+s_d+s_pid = 4608+128+128, s_scr 6144) = 32768 + 6144
    const size_t lds_bytes = 32768 + 6144;   // 38912 -> 3-4 blocks/CU
    pair_embed_mfma<<<grid, 512, lds_bytes, stream>>>(
        anum, row_index, col_index, dist, b2, ws, out, n_edges);
}

// Round 10
// 194.446 us; speedup vs baseline: 2.6709x; 1.0051x over previous
//
#include <hip/hip_runtime.h>
#include <hip/hip_bf16.h>
#include <math.h>

#define NGAUSS   50
#define HID      512
#define EMBD     256
#define NPID     10000         // 100*100 pair types
#define EBLK     32            // edges per block
#define EPAD     264           // u16 stride for emb stage rows in P-GEMM (528B)

typedef __attribute__((ext_vector_type(8))) short   bfrag;   // 8 bf16
typedef __attribute__((ext_vector_type(4))) float   facc;    // 4 f32
typedef __attribute__((ext_vector_type(8))) unsigned short u16x8;
typedef __attribute__((ext_vector_type(4))) unsigned short u16x4;

// ---- workspace layout (bytes) ----
#define PBF_OFF    0                         // u16 [10000*512]      10,240,000 (PERMUTED rows)
#define WC32_OFF   10240000                  // f32 [51*512] (row50 = combined bias) 104,448
#define W1BF_OFF   10344448                  // u16 [8*32*64*8]         262,144
#define WRBF_OFF   10606592                  // u16 [2*32*64*8]          65,536
#define WCBF_OFF   10672128                  // u16 [2*32*64*8]          65,536
#define W2F_OFF    10737664                  // u16 [16*64*8]            16,384

static __device__ __forceinline__ unsigned short f2bf(float f) {
    union { float f; unsigned u; } v; v.f = f;
    unsigned r = v.u + 0x7FFF + ((v.u >> 16) & 1);   // RTNE
    return (unsigned short)(r >> 16);
}
static __device__ __forceinline__ unsigned pack2bf(float a, float b) {
    __hip_bfloat162 t = __float22bfloat162_rn(make_float2(a, b));
    return *reinterpret_cast<unsigned*>(&t);
}
static __device__ __forceinline__ float bfu_lo(unsigned u) {
    union { unsigned u; float f; } v; v.u = u << 16; return v.f;
}
static __device__ __forceinline__ float bfu_hi(unsigned u) {
    union { unsigned u; float f; } v; v.u = u & 0xFFFF0000u; return v.f;
}
// raw hardware 2^x (1 instruction; inf/0 tails give correct sigmoid limits)
static __device__ __forceinline__ float hw_exp2(float x) {
    float r; asm("v_exp_f32 %0, %1" : "=v"(r) : "v"(x)); return r;
}

// ================= K0: Wcomb = W_rbf@W1top (fp32, row50 = b_rbf@W1top + b1), pack W1bot/Wrbf/W2 frags =================
// Fragment (kt,nt): elem j of lane l = W[k = kt*32 + (l>>4)*8 + j][col = nt*16 + (l&15)]
__global__ __launch_bounds__(256) void prep0(
    const float* __restrict__ W_rbf, const float* __restrict__ b_rbf,
    const float* __restrict__ W1, const float* __restrict__ b1,
    const float* __restrict__ W2, char* __restrict__ ws)
{
    const int b = blockIdx.x, tid = threadIdx.x;
    if (b < 102) {
        const int j = b >> 1, chalf = b & 1;
        const int c = chalf * 256 + tid;
        const float* row = (j < NGAUSS) ? &W_rbf[(size_t)j * HID] : b_rbf;
        float a0 = 0.f, a1 = 0.f, a2 = 0.f, a3 = 0.f;
        for (int k = 0; k < HID; k += 4) {
            a0 += row[k + 0] * W1[(size_t)(k + 0) * HID + c];
            a1 += row[k + 1] * W1[(size_t)(k + 1) * HID + c];
            a2 += row[k + 2] * W1[(size_t)(k + 2) * HID + c];
            a3 += row[k + 3] * W1[(size_t)(k + 3) * HID + c];
        }
        float acc = (a0 + a1) + (a2 + a3);
        ((float*)(ws + WC32_OFF))[j * HID + c] = (j < NGAUSS) ? acc : acc + b1[c];
    } else if (b < 166) {
        const int gid = (b - 102) * 256 + tid;          // [0, 16384)
        const int lane = gid & 63, tmp = gid >> 6, nt = tmp & 31, kt = tmp >> 5;
        const int c  = nt * 16 + (lane & 15);
        const int kb = HID + kt * 32 + ((lane >> 4) << 3);
        unsigned short* dst = (unsigned short*)(ws + W1BF_OFF);
        #pragma unroll
        for (int j = 0; j < 8; ++j)
            dst[(size_t)gid * 8 + j] = f2bf(W1[(size_t)(kb + j) * HID + c]);
    } else if (b < 182) {
        const int gid = (b - 166) * 256 + tid;          // [0, 4096)
        const int lane = gid & 63, tmp = gid >> 6, nt = tmp & 31, kt = tmp >> 5;
        const int c  = nt * 16 + (lane & 15);
        const int kb = kt * 32 + ((lane >> 4) << 3);
        unsigned short* dst = (unsigned short*)(ws + WRBF_OFF);
        #pragma unroll
        for (int j = 0; j < 8; ++j) {
            int k = kb + j;
            unsigned short v = 0;
            if (k < NGAUSS)       v = f2bf(W_rbf[(size_t)k * HID + c]);
            else if (k == NGAUSS) v = f2bf(b_rbf[c]);
            dst[(size_t)gid * 8 + j] = v;
        }
    } else {
        const int gid = (b - 182) * 256 + tid;          // [0, 1024)
        const int lane = gid & 63, kt = gid >> 6;
        const int col = lane & 15;
        const int kb  = kt * 32 + ((lane >> 4) << 3);
        unsigned short* dst = (unsigned short*)(ws + W2F_OFF);
        #pragma unroll
        for (int j = 0; j < 8; ++j)
            dst[(size_t)gid * 8 + j] = (col < 8) ? f2bf(W2[(size_t)(kb + j) * 8 + col]) : (unsigned short)0;
    }
}

// ================= K1: pack Wcomb frags (row50 = bias) + P = emb_table @ W1bot =================
// P rows stored PERMUTED: element for hidden col c = Wd*64 + Md*16 + Ld*4 + Jd
// goes to offset Wd*64 + Ld*16 + Md*4 + Jd.
__global__ __launch_bounds__(512) void prep1(
    const float* __restrict__ emb_table, char* __restrict__ ws)
{
    const int b = blockIdx.x, t = threadIdx.x;
    if (b < 8) {
        const int gid = b * 512 + t;                    // [0, 4096)
        const int lane = gid & 63, tmp = gid >> 6, nt = tmp & 31, kt = tmp >> 5;
        const int c  = nt * 16 + (lane & 15);
        const int kb = kt * 32 + ((lane >> 4) << 3);
        const float* wc = (const float*)(ws + WC32_OFF);
        unsigned short* dst = (unsigned short*)(ws + WCBF_OFF);
        #pragma unroll
        for (int j = 0; j < 8; ++j) {
            int k = kb + j;
            dst[(size_t)gid * 8 + j] = (k <= NGAUSS) ? f2bf(wc[k * HID + c]) : (unsigned short)0;
        }
        return;
    }
    __shared__ unsigned short s_e[64 * EPAD];
    const int pb = b - 8;                               // 0..156
    const int lane = t & 63, w = t >> 6;
    const int lq = lane >> 4, lr = lane & 15;
    {
        int row = t >> 3;
        int grow = pb * 64 + row; if (grow >= NPID) grow = NPID - 1;
        int c0 = (t & 7) * 32;
        #pragma unroll
        for (int ii = 0; ii < 8; ++ii) {
            const float4 v = *(const float4*)&emb_table[(size_t)grow * EMBD + c0 + ii * 4];
            u16x4 bv; bv[0] = f2bf(v.x); bv[1] = f2bf(v.y); bv[2] = f2bf(v.z); bv[3] = f2bf(v.w);
            *(u16x4*)&s_e[row * EPAD + c0 + ii * 4] = bv;
        }
    }
    __syncthreads();
    const int ntb = w * 4;
    const unsigned short* W1bf = (const unsigned short*)(ws + W1BF_OFF);
    unsigned short* Pbf = (unsigned short*)(ws + PBF_OFF);
    facc acc[4][4] = {};
    for (int kt = 0; kt < 8; ++kt) {
        bfrag a[4];
        #pragma unroll
        for (int mt = 0; mt < 4; ++mt)
            a[mt] = *(const bfrag*)&s_e[(mt * 16 + lr) * EPAD + kt * 32 + lq * 8];
        #pragma unroll
        for (int ntl = 0; ntl < 4; ++ntl) {
            bfrag bv = *(const bfrag*)&W1bf[((size_t)(kt * 32 + ntb + ntl) * 64 + lane) * 8];
            #pragma unroll
            for (int mt = 0; mt < 4; ++mt)
                acc[mt][ntl] = __builtin_amdgcn_mfma_f32_16x16x32_bf16(a[mt], bv, acc[mt][ntl], 0, 0, 0);
        }
    }
    #pragma unroll
    for (int ntl = 0; ntl < 4; ++ntl) {
        const int col = (ntb + ntl) * 16 + lr;
        const int Wd = col >> 6, Md = (col >> 4) & 3, Ld = (col >> 2) & 3, Jd = col & 3;
        const int off = Wd * 64 + Ld * 16 + Md * 4 + Jd;   // permuted position
        #pragma unroll
        for (int mt = 0; mt < 4; ++mt) {
            #pragma unroll
            for (int r = 0; r < 4; ++r) {
                int grow = pb * 64 + mt * 16 + lq * 4 + r;
                if (grow < NPID) Pbf[(size_t)grow * HID + off] = f2bf(acc[mt][ntl][r]);
            }
        }
    }
}

// ================= main fused kernel: 512 threads, 8 waves x 64 cols; EBLK=32; m-outer loop =================
// g stored FRAG-LINEAR: s_gf[tile*1024 + kt*512 + lane*8 + j] -> 4 hoisted ds_read_b128/thread, 0 conflicts.
// h frag-linear: s_buf[tile*8192 + (kt*64 + l)*8 + j].
__global__ __launch_bounds__(512, 6) void pair_embed_mfma(
    const int* __restrict__ anum,
    const int* __restrict__ row_index,
    const int* __restrict__ col_index,
    const float* __restrict__ dist,
    const float* __restrict__ b2,
    const char* __restrict__ ws,
    float* __restrict__ out,
    int n)
{
    extern __shared__ char smem[];
    unsigned short* s_buf = (unsigned short*)smem;                    // 32 KB frag-linear h (2 tiles)
    unsigned short* s_gf  = (unsigned short*)(smem + 32768);          // 4 KB frag-linear g
    float*          s_scr = (float*)(smem + 32768);                   // 6 KB phase-4 partials (ALIAS, after barrier)
    float*          s_d   = (float*)(smem + 32768 + 4096);
    int*            s_pid = (int*)(smem + 32768 + 4096 + 128);

    const unsigned short* Pbf   = (const unsigned short*)(ws + PBF_OFF);
    const unsigned short* Wrbff = (const unsigned short*)(ws + WRBF_OFF);
    const unsigned short* Wcbf  = (const unsigned short*)(ws + WCBF_OFF);
    const unsigned short* W2f   = (const unsigned short*)(ws + W2F_OFF);

    const int t = threadIdx.x, lane = t & 63, w = t >> 6;   // w 0..7
    const int e0 = blockIdx.x * EBLK;
    const int lq = lane >> 4, lr = lane & 15;

    // ---- phase 0: metadata ----
    if (t < EBLK) {
        int e = e0 + t; if (e >= n) e = n - 1;
        s_d[t] = dist[e];
        s_pid[t] = anum[row_index[e]] + 100 * anum[col_index[e]];
    }
    __syncthreads();

    // ---- phase 1: gaussians, written FRAG-LINEAR (K padded to 64; slot 50 = 1.0 bias row) ----
    {
        const float sp = 12.0f / 49.0f;
        const float coeff = -0.5f / (sp * sp);
        const int e = t >> 4, j0 = (t & 15) * 4;
        const float d = s_d[e];
        float gv[4];
        #pragma unroll
        for (int j = 0; j < 4; ++j) {
            int jj = j0 + j;
            float v = d - (float)jj * sp;
            gv[j] = (jj < NGAUSS) ? __expf(coeff * v * v) : (jj == NGAUSS ? 1.0f : 0.0f);
        }
        // (e,k) -> tile = e>>4, kt = j0>>5, lane' = ((j0>>3)&3)*16 + (e&15), j = j0&7
        const int off = (e >> 4) * 1024 + (j0 >> 5) * 512 + (((j0 >> 3) & 3) * 16 + (e & 15)) * 8 + (j0 & 7);
        uint2 pk; pk.x = pack2bf(gv[0], gv[1]); pk.y = pack2bf(gv[2], gv[3]);
        *(uint2*)&s_gf[off] = pk;
    }

    // pid->P bases (u16 index)
    const unsigned poff0 = (unsigned)s_pid[lr] * 512u;
    const unsigned poff1 = (unsigned)s_pid[16 + lr] * 512u;
    const int pcol = w * 64 + lq * 16;      // + m*4
    __syncthreads();    // g visible

    // ---- hoisted g fragments: 4 ds_read_b128, constant addresses, live whole loop ----
    const bfrag g00 = *(const bfrag*)&s_gf[lane * 8];              // tile0 kt0
    const bfrag g01 = *(const bfrag*)&s_gf[512 + lane * 8];        // tile0 kt1
    const bfrag g10 = *(const bfrag*)&s_gf[1024 + lane * 8];       // tile1 kt0
    const bfrag g11 = *(const bfrag*)&s_gf[1536 + lane * 8];       // tile1 kt1

    // ---- main: m-outer (4 hidden 16-col tiles per wave), 2 edge-tiles inner ----
    for (int m = 0; m < 4; ++m) {
        const uint2 p0 = *(const uint2*)&Pbf[poff0 + pcol + m * 4];
        const uint2 p1 = *(const uint2*)&Pbf[poff1 + pcol + m * 4];
        const int nt = w * 4 + m;
        const bfrag aR0 = *(const bfrag*)&Wrbff[((size_t)(0 * 32 + nt) * 64 + lane) * 8];
        const bfrag aR1 = *(const bfrag*)&Wrbff[((size_t)(1 * 32 + nt) * 64 + lane) * 8];
        const bfrag aC0 = *(const bfrag*)&Wcbf [((size_t)(0 * 32 + nt) * 64 + lane) * 8];
        const bfrag aC1 = *(const bfrag*)&Wcbf [((size_t)(1 * 32 + nt) * 64 + lane) * 8];

        facc racc0 = {}, cacc0 = {}, racc1 = {}, cacc1 = {};
        racc0 = __builtin_amdgcn_mfma_f32_16x16x32_bf16(aR0, g00, racc0, 0, 0, 0);
        cacc0 = __builtin_amdgcn_mfma_f32_16x16x32_bf16(aC0, g00, cacc0, 0, 0, 0);
        racc0 = __builtin_amdgcn_mfma_f32_16x16x32_bf16(aR1, g01, racc0, 0, 0, 0);
        cacc0 = __builtin_amdgcn_mfma_f32_16x16x32_bf16(aC1, g01, cacc0, 0, 0, 0);
        racc1 = __builtin_amdgcn_mfma_f32_16x16x32_bf16(aR0, g10, racc1, 0, 0, 0);
        cacc1 = __builtin_amdgcn_mfma_f32_16x16x32_bf16(aC0, g10, cacc1, 0, 0, 0);
        racc1 = __builtin_amdgcn_mfma_f32_16x16x32_bf16(aR1, g11, racc1, 0, 0, 0);
        cacc1 = __builtin_amdgcn_mfma_f32_16x16x32_bf16(aC1, g11, cacc1, 0, 0, 0);

        unsigned short* hb = s_buf + w * 1024 + m * 256 + (lq >> 1) * 128 + lr * 8 + (lq & 1) * 4;
        {   // tile 0 epilogue
            facc pf; pf[0] = bfu_lo(p0.x); pf[1] = bfu_hi(p0.x); pf[2] = bfu_lo(p0.y); pf[3] = bfu_hi(p0.y);
            facc pre = cacc0 + pf;
            facc nx  = pre * -1.442695040888963f;
            facc ex; ex[0] = hw_exp2(nx[0]); ex[1] = hw_exp2(nx[1]); ex[2] = hw_exp2(nx[2]); ex[3] = hw_exp2(nx[3]);
            facc den = ex + 1.0f;
            facc sg; sg[0] = __builtin_amdgcn_rcpf(den[0]); sg[1] = __builtin_amdgcn_rcpf(den[1]);
                     sg[2] = __builtin_amdgcn_rcpf(den[2]); sg[3] = __builtin_amdgcn_rcpf(den[3]);
            facc h = pre * sg * racc0;
            uint2 hw; hw.x = pack2bf(h[0], h[1]); hw.y = pack2bf(h[2], h[3]);
            *(uint2*)&hb[0] = hw;
        }
        {   // tile 1 epilogue
            facc pf; pf[0] = bfu_lo(p1.x); pf[1] = bfu_hi(p1.x); pf[2] = bfu_lo(p1.y); pf[3] = bfu_hi(p1.y);
            facc pre = cacc1 + pf;
            facc nx  = pre * -1.442695040888963f;
            facc ex; ex[0] = hw_exp2(nx[0]); ex[1] = hw_exp2(nx[1]); ex[2] = hw_exp2(nx[2]); ex[3] = hw_exp2(nx[3]);
            facc den = ex + 1.0f;
            facc sg; sg[0] = __builtin_amdgcn_rcpf(den[0]); sg[1] = __builtin_amdgcn_rcpf(den[1]);
                     sg[2] = __builtin_amdgcn_rcpf(den[2]); sg[3] = __builtin_amdgcn_rcpf(den[3]);
            facc h = pre * sg * racc1;
            uint2 hw; hw.x = pack2bf(h[0], h[1]); hw.y = pack2bf(h[2], h[3]);
            *(uint2*)&hb[8192] = hw;
        }
    }
    __syncthreads();

    // ---- phase 4: out[head][e] = (W2^T @ h^T) + b2; waves = nt(2) x ks(4), 4 kt each ----
    {
        const int nt4 = w & 1;          // 16-edge tile
        const int ks  = w >> 1;         // k-quarter (4 kt each; K=512 -> 16 kt)
        const unsigned short* hbuf = s_buf + nt4 * 8192;
        facc a4 = {};
        #pragma unroll
        for (int kq = 0; kq < 4; ++kq) {
            int kt = ks * 4 + kq;
            bfrag hfrag = *(const bfrag*)&hbuf[(kt * 64 + lane) * 8];
            bfrag wfrag = *(const bfrag*)&W2f[((size_t)kt * 64 + lane) * 8];
            a4 = __builtin_amdgcn_mfma_f32_16x16x32_bf16(wfrag, hfrag, a4, 0, 0, 0);
        }
        if (ks > 0) *(facc*)&s_scr[(((ks - 1) * 2 + nt4) * 64 + lane) * 4] = a4;
        __syncthreads();
        if (ks == 0) {
            #pragma unroll
            for (int p = 0; p < 3; ++p) {
                facc oth = *(const facc*)&s_scr[((size_t)(p * 2 + nt4) * 64 + lane) * 4];
                a4 += oth;
            }
            if (lq < 2) {
                const int e = e0 + nt4 * 16 + lr;
                if (e < n) {
                    #pragma unroll
                    for (int r = 0; r < 4; ++r) {
                        int head = lq * 4 + r;
                        out[(size_t)head * n + e] = a4[r] + b2[head];
                    }
                }
            }
        }
    }
}

extern "C" void kernel_launch(void* const* d_in, const int* in_sizes, int n_in,
                              void* d_out, int out_size, void* d_ws, size_t ws_size,
                              hipStream_t stream) {
    const int*   anum      = (const int*)d_in[0];
    const int*   row_index = (const int*)d_in[1];
    const int*   col_index = (const int*)d_in[2];
    const float* dist      = (const float*)d_in[3];
    const float* W_rbf     = (const float*)d_in[4];
    const float* b_rbf     = (const float*)d_in[5];
    const float* emb_table = (const float*)d_in[6];
    const float* W1        = (const float*)d_in[7];
    const float* b1        = (const float*)d_in[8];
    const float* W2        = (const float*)d_in[9];
    const float* b2        = (const float*)d_in[10];
    float* out = (float*)d_out;
    char* ws = (char*)d_ws;

    const int n_edges = in_sizes[3];

    prep0<<<186, 256, 0, stream>>>(W_rbf, b_rbf, W1, b1, W2, ws);
    prep1<<<8 + 157, 512, 0, stream>>>(emb_table, ws);

    const int grid = (n_edges + EBLK - 1) / EBLK;
    // s_buf 32768 + max(s_gf 4096 + s_d 128 + s_pid 128, s_scr 6144) = 32768 + 6144
    const size_t lds_bytes = 32768 + 6144;   // 38912
    pair_embed_mfma<<<grid, 512, lds_bytes, stream>>>(
        anum, row_index, col_index, dist, b2, ws, out, n_edges);
}